// Round 2
// baseline (149813.171 us; speedup 1.0000x reference)
//
#include <hip/hip_runtime.h>
#include <math.h>

#define TSTEPS 512
#define NBATCH 256
#define DLL 300
#define DAA 74
#define DVV 35
#define DX  409
#define DH  128
#define DMEM 256
#define CST 768   // 6*DH

typedef unsigned short u16;
typedef unsigned int   u32;
typedef float v2f __attribute__((ext_vector_type(2)));

__device__ __forceinline__ float ulo(u32 u){ return __uint_as_float(u<<16); }
__device__ __forceinline__ float uhi(u32 u){ return __uint_as_float(u & 0xffff0000u); }
__device__ __forceinline__ void fma2(v2f &acc, u32 u, float x){ acc.x += x*ulo(u); acc.y += x*uhi(u); }
__device__ __forceinline__ float sigf(float x){ return 1.0f/(1.0f+expf(-x)); }

// dst[k*OUT + o] = bf16(src[o*IN + k])   (transpose to [K][OUT] for coalesced GEMV)
__global__ void cast_transpose(const float* __restrict__ src, u16* __restrict__ dst,
                               int OUT, int IN){
  int idx = blockIdx.x*blockDim.x + threadIdx.x;
  int total = OUT*IN;
  if (idx >= total) return;
  int k = idx / OUT;
  int o = idx - k*OUT;
  float v = src[o*IN + k];
  u32 u = __float_as_uint(v);
  u32 r = (u + 0x7fffu + ((u>>16)&1u)) >> 16;   // RNE
  dst[idx] = (u16)r;
}

// acc over k in [ks,ke): acc.{x,y} += act[k] * W[k][2*col + {0,1}], W as u32 pairs, OUTh = OUT/2
template<int OUTh>
__device__ __forceinline__ void gemv2(const u16* __restrict__ w, const float* __restrict__ act,
                                      int ks, int ke, int col, v2f &acc){
  const u32* __restrict__ wp = (const u32*)w + (size_t)ks*OUTh + col;
  int k = ks;
  for (; k<ke && (k&3); k++){ u32 u = *wp; wp += OUTh; acc.x += act[k]*ulo(u); acc.y += act[k]*uhi(u); }
  for (; k+3<ke; k+=4){
    float4 a = *(const float4*)&act[k];
    u32 u0 = wp[0], u1 = wp[OUTh], u2 = wp[2*OUTh], u3 = wp[3*OUTh];
    wp += 4*OUTh;
    fma2(acc, u0, a.x); fma2(acc, u1, a.y); fma2(acc, u2, a.z); fma2(acc, u3, a.w);
  }
  for (; k<ke; k++){ u32 u = *wp; wp += OUTh; acc.x += act[k]*ulo(u); acc.y += act[k]*uhi(u); }
}

struct P {
  const float* x;
  const float *bih_l,*bhh_l,*bih_a,*bhh_a,*bih_v,*bhh_v;
  const float *a1b1,*a1b2,*a2b1,*a2b2,*g1b1,*g1b2,*g2b1,*g2b2;
  const float *ob1,*ow2,*ob2;
  const u16 *ihl,*hhl,*iha,*hha,*ihv,*hhv;
  const u16 *a1w1,*a1w2,*a2w1,*a2w2,*g1w1,*g1w2,*g2w1,*g2w2,*ow1;
  float* out;
};

__global__ __launch_bounds__(1024, 4)
void mfn_persistent(P p){
  __shared__ __align__(16) float s_x[420];     // l:[0,300) a:[304,378) v:[384,419)
  __shared__ __align__(16) float s_hl[DH], s_ha[DH], s_hv[DH];
  __shared__ __align__(16) float s_cl[DH], s_ca[DH], s_cv[DH];
  __shared__ __align__(16) float s_mem[DMEM];
  __shared__ __align__(16) float s_cstar[CST];
  __shared__ __align__(16) float s_att[CST];
  __shared__ __align__(16) float s_z[CST];
  __shared__ __align__(16) float s_part[6144];  // A=0, B=2048, C=4096
  __shared__ __align__(16) float s_last[640];
  __shared__ float s_red[4];

  const int tid = threadIdx.x;
  const int n   = blockIdx.x;
  const int g4 = tid>>8, c4 = tid&255;
  const int g8 = tid>>7, c8 = tid&127;

  if (tid < DH){ s_hl[tid]=0.f; s_ha[tid]=0.f; s_hv[tid]=0.f;
                 s_cl[tid]=0.f; s_ca[tid]=0.f; s_cv[tid]=0.f; }
  if (tid < DMEM) s_mem[tid]=0.f;
  // x(0) -> s_x (with alignment-padding remap)
  if (tid < DX){
    int dst = tid + (tid>=DLL?4:0) + (tid>=DLL+DAA?6:0);
    s_x[dst] = p.x[(size_t)n*DX + tid];
  }
  __syncthreads();

  for (int t=0; t<TSTEPS; t++){
    // prefetch next x row into registers (hides under LSTM compute)
    float xreg = 0.f; int xdst = 0;
    if (t+1 < TSTEPS && tid < DX){
      xreg = p.x[((size_t)(t+1)*NBATCH + n)*DX + tid];
      xdst = tid + (tid>=DLL?4:0) + (tid>=DLL+DAA?6:0);
    }

    // ---- phase 1: 3 LSTM gate partials (all 1024 threads) ----
    {
      v2f aL={0.f,0.f}, aA={0.f,0.f}, aV={0.f,0.f};
      gemv2<256>(p.ihl, s_x,      (DLL*g4)>>2, (DLL*(g4+1))>>2, c4, aL);
      gemv2<256>(p.hhl, s_hl,     32*g4, 32*(g4+1), c4, aL);
      gemv2<256>(p.iha, s_x+304,  (DAA*g4)>>2, (DAA*(g4+1))>>2, c4, aA);
      gemv2<256>(p.hha, s_ha,     32*g4, 32*(g4+1), c4, aA);
      gemv2<256>(p.ihv, s_x+384,  (DVV*g4)>>2, (DVV*(g4+1))>>2, c4, aV);
      gemv2<256>(p.hhv, s_hv,     32*g4, 32*(g4+1), c4, aV);
      *(v2f*)&s_part[       g4*512 + 2*c4] = aL;
      *(v2f*)&s_part[2048 + g4*512 + 2*c4] = aA;
      *(v2f*)&s_part[4096 + g4*512 + 2*c4] = aV;
    }
    __syncthreads();                                   // B0

    // write prefetched x (all x reads completed at B0)
    if (t+1 < TSTEPS && tid < DX) s_x[xdst] = xreg;

    // ---- LSTM reduce + activations (tid<384: modality m, unit j) ----
    if (tid < 384){
      int m = tid>>7, j = tid&127;
      const float *bi, *bh, *pb; float *sh, *sc;
      if (m==0){ bi=p.bih_l; bh=p.bhh_l; sh=s_hl; sc=s_cl; pb=s_part; }
      else if (m==1){ bi=p.bih_a; bh=p.bhh_a; sh=s_ha; sc=s_ca; pb=s_part+2048; }
      else { bi=p.bih_v; bh=p.bhh_v; sh=s_hv; sc=s_cv; pb=s_part+4096; }
      float gs[4];
      #pragma unroll
      for (int q=0;q<4;q++){
        int o = q*128 + j;
        gs[q] = bi[o]+bh[o] + pb[o]+pb[512+o]+pb[1024+o]+pb[1536+o];
      }
      float ig=sigf(gs[0]), fg=sigf(gs[1]), gg=tanhf(gs[2]), og=sigf(gs[3]);
      float c_old = sc[j];
      float c = fg*c_old + ig*gg;
      float h = og*tanhf(c);
      s_cstar[tid]     = c_old;
      s_cstar[384+tid] = c;
      sc[j]=c; sh[j]=h;
    }
    __syncthreads();                                   // B1

    // ---- att1_W1: (256,768) partials ----
    {
      v2f acc={0.f,0.f};
      gemv2<128>(p.a1w1, s_cstar, 96*g8, 96*(g8+1), c8, acc);
      *(v2f*)&s_part[g8*256 + 2*c8] = acc;
    }
    __syncthreads();                                   // B2
    if (tid < 256){
      float z = p.a1b1[tid];
      #pragma unroll
      for (int g=0; g<8; g++) z += s_part[g*256 + tid];
      s_z[tid] = fmaxf(z, 0.f);
    }
    __syncthreads();                                   // B3

    // ---- att1_W2: (768,256) partials (768 active threads) ----
    if (tid < 768){
      int g2 = (tid >= 384) ? 1 : 0;
      int c  = tid - 384*g2;
      v2f acc={0.f,0.f};
      gemv2<384>(p.a1w2, s_z, 128*g2, 128*(g2+1), c, acc);
      *(v2f*)&s_part[g2*768 + 2*c] = acc;
    }
    __syncthreads();                                   // B4

    // ---- softmax over 768 + attended ----
    {
      float sc0=-1e30f, sc1=-1e30f, sc2=-1e30f;
      if (tid < 256){
        sc0 = p.a1b2[tid]     + s_part[tid]     + s_part[768+tid];
        sc1 = p.a1b2[tid+256] + s_part[256+tid] + s_part[1024+tid];
        sc2 = p.a1b2[tid+512] + s_part[512+tid] + s_part[1280+tid];
      }
      float m = fmaxf(fmaxf(sc0,sc1),sc2);
      for (int off=32; off; off>>=1) m = fmaxf(m, __shfl_down(m, off));
      if (tid < 256 && (tid&63)==0) s_red[tid>>6]=m;
      __syncthreads();                                 // B5
      m = fmaxf(fmaxf(s_red[0],s_red[1]), fmaxf(s_red[2],s_red[3]));
      float e0=expf(sc0-m), e1=expf(sc1-m), e2=expf(sc2-m);
      float s = e0+e1+e2;
      for (int off=32; off; off>>=1) s += __shfl_down(s, off);
      __syncthreads();                                 // B6
      if (tid < 256 && (tid&63)==0) s_red[tid>>6]=s;
      __syncthreads();                                 // B7
      float inv = 1.0f/(s_red[0]+s_red[1]+s_red[2]+s_red[3]);
      if (tid < 256){
        s_att[tid]     = e0*inv*s_cstar[tid];
        s_att[tid+256] = e1*inv*s_cstar[tid+256];
        s_att[tid+512] = e2*inv*s_cstar[tid+512];
      }
    }
    __syncthreads();                                   // B8

    // ---- fused att2/g1/g2 layer-1 partials (each OUT=256; K=768 att + 256 mem for g) ----
    {
      v2f au={0.f,0.f}, a1={0.f,0.f}, a2={0.f,0.f};
      const int ks = 96*g8;
      const u32* wu = (const u32*)p.a2w1 + (size_t)ks*128 + c8;
      const u32* w1 = (const u32*)p.g1w1 + (size_t)ks*128 + c8;
      const u32* w2 = (const u32*)p.g2w1 + (size_t)ks*128 + c8;
      for (int k=ks; k<ks+96; k+=4){
        float4 a = *(const float4*)&s_att[k];
        u32 x0=wu[0], x1=wu[128], x2=wu[256], x3=wu[384];
        u32 y0=w1[0], y1=w1[128], y2=w1[256], y3=w1[384];
        u32 z0=w2[0], z1=w2[128], z2=w2[256], z3=w2[384];
        fma2(au,x0,a.x); fma2(au,x1,a.y); fma2(au,x2,a.z); fma2(au,x3,a.w);
        fma2(a1,y0,a.x); fma2(a1,y1,a.y); fma2(a1,y2,a.z); fma2(a1,y3,a.w);
        fma2(a2,z0,a.x); fma2(a2,z1,a.y); fma2(a2,z2,a.z); fma2(a2,z3,a.w);
        wu += 512; w1 += 512; w2 += 512;
      }
      const int ms = 32*g8;
      const u32* m1 = (const u32*)p.g1w1 + (size_t)(CST+ms)*128 + c8;
      const u32* m2 = (const u32*)p.g2w1 + (size_t)(CST+ms)*128 + c8;
      for (int k=ms; k<ms+32; k+=4){
        float4 a = *(const float4*)&s_mem[k];
        u32 y0=m1[0], y1=m1[128], y2=m1[256], y3=m1[384];
        u32 z0=m2[0], z1=m2[128], z2=m2[256], z3=m2[384];
        fma2(a1,y0,a.x); fma2(a1,y1,a.y); fma2(a1,y2,a.z); fma2(a1,y3,a.w);
        fma2(a2,z0,a.x); fma2(a2,z1,a.y); fma2(a2,z2,a.z); fma2(a2,z3,a.w);
        m1 += 512; m2 += 512;
      }
      *(v2f*)&s_part[       g8*256 + 2*c8] = au;
      *(v2f*)&s_part[2048 + g8*256 + 2*c8] = a1;
      *(v2f*)&s_part[4096 + g8*256 + 2*c8] = a2;
    }
    __syncthreads();                                   // B9
    if (tid < 256){
      float u=p.a2b1[tid], v1=p.g1b1[tid], v2=p.g2b1[tid];
      #pragma unroll
      for (int g=0; g<8; g++){
        u  += s_part[g*256 + tid];
        v1 += s_part[2048 + g*256 + tid];
        v2 += s_part[4096 + g*256 + tid];
      }
      s_z[tid]     = fmaxf(u ,0.f);
      s_z[256+tid] = fmaxf(v1,0.f);
      s_z[512+tid] = fmaxf(v2,0.f);
    }
    __syncthreads();                                   // B10

    // ---- layer-2s: cHat / gamma1 / gamma2 partials ----
    {
      v2f acc={0.f,0.f};
      gemv2<128>(p.a2w2, s_z,     32*g8, 32*(g8+1), c8, acc);
      *(v2f*)&s_part[g8*256 + 2*c8] = acc;
      v2f acc1={0.f,0.f};
      gemv2<128>(p.g1w2, s_z+256, 32*g8, 32*(g8+1), c8, acc1);
      *(v2f*)&s_part[2048 + g8*256 + 2*c8] = acc1;
      v2f acc2={0.f,0.f};
      gemv2<128>(p.g2w2, s_z+512, 32*g8, 32*(g8+1), c8, acc2);
      *(v2f*)&s_part[4096 + g8*256 + 2*c8] = acc2;
    }
    __syncthreads();                                   // B11
    if (tid < 256){
      float ch=p.a2b2[tid], gm1=p.g1b2[tid], gm2=p.g2b2[tid];
      #pragma unroll
      for (int g=0; g<8; g++){
        ch  += s_part[g*256 + tid];
        gm1 += s_part[2048 + g*256 + tid];
        gm2 += s_part[4096 + g*256 + tid];
      }
      ch = tanhf(ch); gm1 = sigf(gm1); gm2 = sigf(gm2);
      s_mem[tid] = gm1*s_mem[tid] + gm2*ch;
    }
    __syncthreads();                                   // B12 (protects s_part & s_mem for next step)
  }

  // ---- output MLP ----
  if (tid < DH){ s_last[tid]=s_hl[tid]; s_last[DH+tid]=s_ha[tid]; s_last[2*DH+tid]=s_hv[tid]; }
  if (tid < DMEM) s_last[3*DH+tid]=s_mem[tid];
  __syncthreads();
  {
    v2f acc={0.f,0.f};
    gemv2<128>(p.ow1, s_last, 80*g8, 80*(g8+1), c8, acc);
    *(v2f*)&s_part[g8*256 + 2*c8] = acc;
  }
  __syncthreads();
  {
    float pp = 0.f;
    if (tid < 256){
      float z = p.ob1[tid];
      #pragma unroll
      for (int g=0; g<8; g++) z += s_part[g*256 + tid];
      pp = fmaxf(z, 0.f) * p.ow2[tid];
    }
    for (int off=32; off; off>>=1) pp += __shfl_down(pp, off);
    if (tid < 256 && (tid&63)==0) s_red[tid>>6]=pp;
    __syncthreads();
    if (tid==0) p.out[n] = s_red[0]+s_red[1]+s_red[2]+s_red[3] + p.ob2[0];
  }
}

extern "C" void kernel_launch(void* const* d_in, const int* in_sizes, int n_in,
                              void* d_out, int out_size, void* d_ws, size_t ws_size,
                              hipStream_t stream){
  u16* ws = (u16*)d_ws;
  struct M { int src; size_t off; int OUT, IN; };
  const M mats[15] = {
    { 5,       0, 512,  300},   // Wih_l
    { 6,  153600, 512,  128},   // Whh_l
    { 9,  219136, 512,   74},   // Wih_a
    {10,  257024, 512,  128},   // Whh_a
    {13,  322560, 512,   35},   // Wih_v
    {14,  340480, 512,  128},   // Whh_v
    {17,  406016, 256,  768},   // att1_W1
    {19,  602624, 768,  256},   // att1_W2
    {21,  799232, 256,  768},   // att2_W1
    {23,  995840, 256,  256},   // att2_W2
    {25, 1061376, 256, 1024},   // g1_W1
    {27, 1323520, 256,  256},   // g1_W2
    {29, 1389056, 256, 1024},   // g2_W1
    {31, 1651200, 256,  256},   // g2_W2
    {33, 1716736, 256,  640},   // out_W1
  };
  for (int i=0;i<15;i++){
    int total = mats[i].OUT*mats[i].IN;
    cast_transpose<<<(total+255)/256, 256, 0, stream>>>(
        (const float*)d_in[mats[i].src], ws + mats[i].off, mats[i].OUT, mats[i].IN);
  }

  P p;
  p.x     = (const float*)d_in[0];
  p.bih_l = (const float*)d_in[7];  p.bhh_l = (const float*)d_in[8];
  p.bih_a = (const float*)d_in[11]; p.bhh_a = (const float*)d_in[12];
  p.bih_v = (const float*)d_in[15]; p.bhh_v = (const float*)d_in[16];
  p.a1b1  = (const float*)d_in[18]; p.a1b2  = (const float*)d_in[20];
  p.a2b1  = (const float*)d_in[22]; p.a2b2  = (const float*)d_in[24];
  p.g1b1  = (const float*)d_in[26]; p.g1b2  = (const float*)d_in[28];
  p.g2b1  = (const float*)d_in[30]; p.g2b2  = (const float*)d_in[32];
  p.ob1   = (const float*)d_in[34]; p.ow2   = (const float*)d_in[35];
  p.ob2   = (const float*)d_in[36];
  p.ihl   = ws + 0;       p.hhl  = ws + 153600;
  p.iha   = ws + 219136;  p.hha  = ws + 257024;
  p.ihv   = ws + 322560;  p.hhv  = ws + 340480;
  p.a1w1  = ws + 406016;  p.a1w2 = ws + 602624;
  p.a2w1  = ws + 799232;  p.a2w2 = ws + 995840;
  p.g1w1  = ws + 1061376; p.g1w2 = ws + 1323520;
  p.g2w1  = ws + 1389056; p.g2w2 = ws + 1651200;
  p.ow1   = ws + 1716736;
  p.out   = (float*)d_out;

  mfn_persistent<<<NBATCH, 1024, 0, stream>>>(p);
}